// Round 1
// baseline (4196.699 us; speedup 1.0000x reference)
//
#include <hip/hip_runtime.h>
#include <math.h>

#define DD 64   // feature dim

// ---- monotone float<->uint encoding for atomicMax on floats ----
__device__ __forceinline__ unsigned enc_f32(float x){
  unsigned u = __float_as_uint(x);
  return (u & 0x80000000u) ? ~u : (u | 0x80000000u);
}
__device__ __forceinline__ float dec_f32(unsigned u){
  return (u & 0x80000000u) ? __uint_as_float(u & 0x7fffffffu) : __uint_as_float(~u);
}

// q = x@Wq+bq, k = x@Wk+bk, v = x@Wv+bv
// thread = (node, t) with 16 threads/node, each computing 4 output cols
__global__ __launch_bounds__(256) void k_proj3(
    const float* __restrict__ x,
    const float* __restrict__ Wq, const float* __restrict__ bq, float* __restrict__ q,
    const float* __restrict__ Wk, const float* __restrict__ bk, float* __restrict__ k,
    const float* __restrict__ Wv, const float* __restrict__ bv, float* __restrict__ v,
    int n)
{
  int gid = blockIdx.x * blockDim.x + threadIdx.x;
  int node = gid >> 4;
  if (node >= n) return;
  int t = (gid & 15) << 2;
  const float* xr = x + (size_t)node * DD;
  float4 aq = *(const float4*)(bq + t);
  float4 ak = *(const float4*)(bk + t);
  float4 av = *(const float4*)(bv + t);
  for (int i = 0; i < DD; i += 4) {
    float4 xv = *(const float4*)(xr + i);
    #pragma unroll
    for (int u = 0; u < 4; ++u) {
      float xi = (&xv.x)[u];
      const size_t ro = (size_t)(i + u) * DD + t;
      float4 wq = *(const float4*)(Wq + ro);
      float4 wk = *(const float4*)(Wk + ro);
      float4 wv = *(const float4*)(Wv + ro);
      aq.x = fmaf(xi, wq.x, aq.x); aq.y = fmaf(xi, wq.y, aq.y);
      aq.z = fmaf(xi, wq.z, aq.z); aq.w = fmaf(xi, wq.w, aq.w);
      ak.x = fmaf(xi, wk.x, ak.x); ak.y = fmaf(xi, wk.y, ak.y);
      ak.z = fmaf(xi, wk.z, ak.z); ak.w = fmaf(xi, wk.w, ak.w);
      av.x = fmaf(xi, wv.x, av.x); av.y = fmaf(xi, wv.y, av.y);
      av.z = fmaf(xi, wv.z, av.z); av.w = fmaf(xi, wv.w, av.w);
    }
  }
  size_t o = (size_t)node * DD + t;
  *(float4*)(q + o) = aq;
  *(float4*)(k + o) = ak;
  *(float4*)(v + o) = av;
}

// logits[e] = SCALE * dot(q[dst[e]], k[src[e]]); atomicMax into m_enc[dst]
// 16 lanes per edge, float4 each, shfl_xor reduce within the 16-lane group
__global__ __launch_bounds__(256) void k_logits(
    const float* __restrict__ q, const float* __restrict__ k,
    const int* __restrict__ src, const int* __restrict__ dst,
    float* __restrict__ logits, unsigned* __restrict__ m_enc, int ecnt)
{
  int gid = blockIdx.x * blockDim.x + threadIdx.x;
  int e = gid >> 4;
  if (e >= ecnt) return;
  int t = (gid & 15) << 2;
  int s = src[e], d = dst[e];
  float4 qv = *(const float4*)(q + (size_t)d * DD + t);
  float4 kv = *(const float4*)(k + (size_t)s * DD + t);
  float p = qv.x*kv.x + qv.y*kv.y + qv.z*kv.z + qv.w*kv.w;
  p += __shfl_xor(p, 1);
  p += __shfl_xor(p, 2);
  p += __shfl_xor(p, 4);
  p += __shfl_xor(p, 8);
  if ((gid & 15) == 0) {
    p *= 0.125f;  // 1/sqrt(64)
    logits[e] = p;
    atomicMax(m_enc + d, enc_f32(p));
  }
}

// w = exp(logits - m[dst]); denom[dst] += w; agg[dst] += w * v[src]
__global__ __launch_bounds__(256) void k_scatter(
    const float* __restrict__ v,
    const int* __restrict__ src, const int* __restrict__ dst,
    const float* __restrict__ logits, const unsigned* __restrict__ m_enc,
    float* __restrict__ denom, float* __restrict__ agg, int ecnt)
{
  int gid = blockIdx.x * blockDim.x + threadIdx.x;
  int e = gid >> 4;
  if (e >= ecnt) return;
  int t = (gid & 15) << 2;
  int s = src[e], d = dst[e];
  float m = dec_f32(m_enc[d]);
  float w = expf(logits[e] - m);
  if ((gid & 15) == 0) atomicAdd(denom + d, w);
  float4 vv = *(const float4*)(v + (size_t)s * DD + t);
  float* ap = agg + (size_t)d * DD + t;
  atomicAdd(ap + 0, w * vv.x);
  atomicAdd(ap + 1, w * vv.y);
  atomicAdd(ap + 2, w * vv.z);
  atomicAdd(ap + 3, w * vv.w);
}

// out = relu(agg/denom + x@Ws + bs)   (denom==0 -> agg term is 0)
__global__ __launch_bounds__(256) void k_out(
    const float* __restrict__ x,
    const float* __restrict__ Ws, const float* __restrict__ bs,
    const float* __restrict__ agg, const float* __restrict__ denom,
    float* __restrict__ out, int n)
{
  int gid = blockIdx.x * blockDim.x + threadIdx.x;
  int node = gid >> 4;
  if (node >= n) return;
  int t = (gid & 15) << 2;
  const float* xr = x + (size_t)node * DD;
  float4 a = *(const float4*)(bs + t);
  for (int i = 0; i < DD; i += 4) {
    float4 xv = *(const float4*)(xr + i);
    #pragma unroll
    for (int u = 0; u < 4; ++u) {
      float xi = (&xv.x)[u];
      float4 w = *(const float4*)(Ws + (size_t)(i + u) * DD + t);
      a.x = fmaf(xi, w.x, a.x); a.y = fmaf(xi, w.y, a.y);
      a.z = fmaf(xi, w.z, a.z); a.w = fmaf(xi, w.w, a.w);
    }
  }
  float dn = denom[node];
  float inv = (dn > 0.f) ? (1.0f / dn) : 0.f;
  float4 ag = *(const float4*)(agg + (size_t)node * DD + t);
  float4 r;
  r.x = fmaxf(fmaf(ag.x, inv, a.x), 0.f);
  r.y = fmaxf(fmaf(ag.y, inv, a.y), 0.f);
  r.z = fmaxf(fmaf(ag.z, inv, a.z), 0.f);
  r.w = fmaxf(fmaf(ag.w, inv, a.w), 0.f);
  *(float4*)(out + (size_t)node * DD + t) = r;
}

// batch is sorted: run-length accumulate per wave (64 dims), flush on graph change
__global__ __launch_bounds__(64) void k_pool_sum(
    const float* __restrict__ x, const int* __restrict__ batch,
    float* __restrict__ gsum, float* __restrict__ gcnt, int n)
{
  int lane = threadIdx.x;
  int n0 = blockIdx.x * 64;
  if (n0 >= n) return;
  int n1 = min(n0 + 64, n);
  float acc = 0.f;
  int g_prev = batch[n0];
  int run = 0;
  for (int nn = n0; nn < n1; ++nn) {
    int g = batch[nn];
    if (g != g_prev) {
      atomicAdd(gsum + (size_t)g_prev * DD + lane, acc);
      if (lane == 0) atomicAdd(gcnt + g_prev, (float)run);
      acc = 0.f; run = 0; g_prev = g;
    }
    acc += x[(size_t)nn * DD + lane];
    run++;
  }
  atomicAdd(gsum + (size_t)g_prev * DD + lane, acc);
  if (lane == 0) atomicAdd(gcnt + g_prev, (float)run);
}

__global__ __launch_bounds__(256) void k_pool_div(
    const float* __restrict__ gsum, const float* __restrict__ gcnt,
    float* __restrict__ emb, int gtot)
{
  int gid = blockIdx.x * blockDim.x + threadIdx.x;
  if (gid >= gtot * DD) return;
  int g = gid >> 6;
  emb[gid] = gsum[gid] / fmaxf(gcnt[g], 1.0f);
}

extern "C" void kernel_launch(void* const* d_in, const int* in_sizes, int n_in,
                              void* d_out, int out_size, void* d_ws, size_t ws_size,
                              hipStream_t stream)
{
  const float* x_in  = (const float*)d_in[0];
  const int*   ei    = (const int*)  d_in[1];
  const int*   batch = (const int*)  d_in[2];
  const float* Wq = (const float*)d_in[3];
  const float* bq = (const float*)d_in[4];
  const float* Wk = (const float*)d_in[5];
  const float* bk = (const float*)d_in[6];
  const float* Wv = (const float*)d_in[7];
  const float* bv = (const float*)d_in[8];
  const float* Ws = (const float*)d_in[9];
  const float* bs = (const float*)d_in[10];

  const int nd     = in_sizes[0];            // N*D
  const int n      = nd / DD;                // N
  const int ecnt   = in_sizes[1] / 2;        // E
  const int layers = in_sizes[3] / (DD * DD);// L
  const int gtot   = (out_size - nd) / DD;   // G

  const int* src = ei;
  const int* dst = ei + ecnt;

  float* P0 = (float*)d_ws;
  float* P1 = P0 + (size_t)nd;
  float* Q  = P1 + (size_t)nd;
  float* K  = Q  + (size_t)nd;
  float* V  = K  + (size_t)nd;
  float* logits = V + (size_t)nd;
  unsigned* m_enc = (unsigned*)(logits + (size_t)ecnt);
  float* denom = (float*)m_enc + (size_t)n;
  float* gsum  = denom + (size_t)n;
  float* gcnt  = gsum + (size_t)gtot * DD;

  float* out = (float*)d_out;

  const int pb = (n * 16 + 255) / 256;
  const int eb = (ecnt * 16 + 255) / 256;

  const float* xcur = x_in;
  for (int l = 0; l < layers; ++l) {
    float* agg   = (l & 1) ? P1 : P0;
    float* xnext = (l == layers - 1) ? out : agg;

    hipMemsetAsync(agg,   0, (size_t)nd * 4, stream);
    hipMemsetAsync(m_enc, 0, (size_t)n * 4, stream);
    hipMemsetAsync(denom, 0, (size_t)n * 4, stream);

    const size_t wo = (size_t)l * DD * DD;
    const size_t bo = (size_t)l * DD;
    k_proj3<<<pb, 256, 0, stream>>>(xcur, Wq + wo, bq + bo, Q,
                                    Wk + wo, bk + bo, K,
                                    Wv + wo, bv + bo, V, n);
    k_logits<<<eb, 256, 0, stream>>>(Q, K, src, dst, logits, m_enc, ecnt);
    k_scatter<<<eb, 256, 0, stream>>>(V, src, dst, logits, m_enc, denom, agg, ecnt);
    k_out<<<pb, 256, 0, stream>>>(xcur, Ws + wo, bs + bo, agg, denom, xnext, n);
    xcur = xnext;
  }

  hipMemsetAsync(gsum, 0, (size_t)gtot * DD * 4, stream);
  hipMemsetAsync(gcnt, 0, (size_t)gtot * 4, stream);
  const int nb = (n + 63) / 64;
  k_pool_sum<<<nb, 64, 0, stream>>>(out, batch, gsum, gcnt, n);
  const int fb = (gtot * DD + 255) / 256;
  k_pool_div<<<fb, 256, 0, stream>>>(gsum, gcnt, out + (size_t)nd, gtot);
}

// Round 2
// 1286.403 us; speedup vs baseline: 3.2624x; 3.2624x over previous
//
#include <hip/hip_runtime.h>
#include <math.h>

#define DD 64   // feature dim

// q = x@Wq+bq, k = x@Wk+bk, v = x@Wv+bv
// thread = (node, t) with 16 threads/node, each computing 4 output cols
__global__ __launch_bounds__(256) void k_proj3(
    const float* __restrict__ x,
    const float* __restrict__ Wq, const float* __restrict__ bq, float* __restrict__ q,
    const float* __restrict__ Wk, const float* __restrict__ bk, float* __restrict__ k,
    const float* __restrict__ Wv, const float* __restrict__ bv, float* __restrict__ v,
    int n)
{
  int gid = blockIdx.x * blockDim.x + threadIdx.x;
  int node = gid >> 4;
  if (node >= n) return;
  int t = (gid & 15) << 2;
  const float* xr = x + (size_t)node * DD;
  float4 aq = *(const float4*)(bq + t);
  float4 ak = *(const float4*)(bk + t);
  float4 av = *(const float4*)(bv + t);
  for (int i = 0; i < DD; i += 4) {
    float4 xv = *(const float4*)(xr + i);
    #pragma unroll
    for (int u = 0; u < 4; ++u) {
      float xi = (&xv.x)[u];
      const size_t ro = (size_t)(i + u) * DD + t;
      float4 wq = *(const float4*)(Wq + ro);
      float4 wk = *(const float4*)(Wk + ro);
      float4 wv = *(const float4*)(Wv + ro);
      aq.x = fmaf(xi, wq.x, aq.x); aq.y = fmaf(xi, wq.y, aq.y);
      aq.z = fmaf(xi, wq.z, aq.z); aq.w = fmaf(xi, wq.w, aq.w);
      ak.x = fmaf(xi, wk.x, ak.x); ak.y = fmaf(xi, wk.y, ak.y);
      ak.z = fmaf(xi, wk.z, ak.z); ak.w = fmaf(xi, wk.w, ak.w);
      av.x = fmaf(xi, wv.x, av.x); av.y = fmaf(xi, wv.y, av.y);
      av.z = fmaf(xi, wv.z, av.z); av.w = fmaf(xi, wv.w, av.w);
    }
  }
  size_t o = (size_t)node * DD + t;
  *(float4*)(q + o) = aq;
  *(float4*)(k + o) = ak;
  *(float4*)(v + o) = av;
}

// ---- CSR build (once per call) ----
__global__ __launch_bounds__(256) void k_hist(
    const int* __restrict__ dst, int* __restrict__ deg, int ecnt)
{
  for (int e = blockIdx.x * blockDim.x + threadIdx.x; e < ecnt;
       e += gridDim.x * blockDim.x)
    atomicAdd(deg + dst[e], 1);
}

// exclusive scan deg[0..n) -> rowptr[0..n], single workgroup, wave-level
__global__ __launch_bounds__(1024) void k_scan(
    const int* __restrict__ deg, int* __restrict__ rowptr, int n)
{
  __shared__ int wsum[16];
  int lane = threadIdx.x & 63;
  int wave = threadIdx.x >> 6;
  if (threadIdx.x == 0) rowptr[0] = 0;
  int carry = 0;
  for (int base = 0; base < n; base += 1024) {
    int i = base + threadIdx.x;
    int val = (i < n) ? deg[i] : 0;
    // wave inclusive scan
    int s = val;
    #pragma unroll
    for (int off = 1; off < 64; off <<= 1) {
      int t = __shfl_up(s, off);
      if (lane >= off) s += t;
    }
    if (lane == 63) wsum[wave] = s;
    __syncthreads();
    if (wave == 0) {
      int ws = (lane < 16) ? wsum[lane] : 0;
      #pragma unroll
      for (int off = 1; off < 16; off <<= 1) {
        int t = __shfl_up(ws, off);
        if (lane >= off) ws += t;
      }
      if (lane < 16) wsum[lane] = ws;
    }
    __syncthreads();
    int woff = (wave > 0) ? wsum[wave - 1] : 0;
    if (i < n) rowptr[i + 1] = carry + woff + s;
    carry += wsum[15];
    __syncthreads();
  }
}

__global__ __launch_bounds__(256) void k_fill(
    const int* __restrict__ src, const int* __restrict__ dst,
    const int* __restrict__ rowptr, int* __restrict__ cur,
    int* __restrict__ adj, int ecnt)
{
  for (int e = blockIdx.x * blockDim.x + threadIdx.x; e < ecnt;
       e += gridDim.x * blockDim.x) {
    int d = dst[e];
    int pos = rowptr[d] + atomicAdd(cur + d, 1);
    adj[pos] = src[e];
  }
}

// one wave per dst node: online-softmax aggregation over incoming edges,
// fused with skip (x@Ws+bs) and relu. lane = feature dim.
__global__ __launch_bounds__(256) void k_node(
    const float* __restrict__ q, const float* __restrict__ k,
    const float* __restrict__ v, const float* __restrict__ x,
    const float* __restrict__ Ws, const float* __restrict__ bs,
    const int* __restrict__ rowptr, const int* __restrict__ adj,
    float* __restrict__ out, int n)
{
  int node = (blockIdx.x * blockDim.x + threadIdx.x) >> 6;
  int lane = threadIdx.x & 63;
  if (node >= n) return;

  float qL = q[(size_t)node * DD + lane];
  float m = -INFINITY, denom = 0.f, agg = 0.f;
  int e0 = rowptr[node], e1 = rowptr[node + 1];
  for (int ei = e0; ei < e1; ++ei) {
    int s = adj[ei];
    float kL = k[(size_t)s * DD + lane];
    float vL = v[(size_t)s * DD + lane];
    float p = qL * kL;
    p += __shfl_xor(p, 1);
    p += __shfl_xor(p, 2);
    p += __shfl_xor(p, 4);
    p += __shfl_xor(p, 8);
    p += __shfl_xor(p, 16);
    p += __shfl_xor(p, 32);
    p *= 0.125f;  // 1/sqrt(64)
    float newm = fmaxf(m, p);
    float c = __expf(m - newm);   // first iter: exp(-inf) = 0
    float w = __expf(p - newm);
    denom = denom * c + w;
    agg = fmaf(agg, c, w * vL);
    m = newm;
  }

  // skip: sL = bs[lane] + sum_i x[node][i] * Ws[i][lane]
  float xi = x[(size_t)node * DD + lane];
  float sL = bs[lane];
  #pragma unroll
  for (int i = 0; i < DD; ++i) {
    float xv = __shfl(xi, i);
    sL = fmaf(xv, Ws[i * DD + lane], sL);
  }

  float r = (denom > 0.f) ? (agg / denom) : 0.f;
  out[(size_t)node * DD + lane] = fmaxf(r + sL, 0.f);
}

// batch is sorted: run-length accumulate per wave (64 dims), flush on graph change
__global__ __launch_bounds__(64) void k_pool_sum(
    const float* __restrict__ x, const int* __restrict__ batch,
    float* __restrict__ gsum, float* __restrict__ gcnt, int n)
{
  int lane = threadIdx.x;
  int n0 = blockIdx.x * 64;
  if (n0 >= n) return;
  int n1 = min(n0 + 64, n);
  float acc = 0.f;
  int g_prev = batch[n0];
  int run = 0;
  for (int nn = n0; nn < n1; ++nn) {
    int g = batch[nn];
    if (g != g_prev) {
      atomicAdd(gsum + (size_t)g_prev * DD + lane, acc);
      if (lane == 0) atomicAdd(gcnt + g_prev, (float)run);
      acc = 0.f; run = 0; g_prev = g;
    }
    acc += x[(size_t)nn * DD + lane];
    run++;
  }
  atomicAdd(gsum + (size_t)g_prev * DD + lane, acc);
  if (lane == 0) atomicAdd(gcnt + g_prev, (float)run);
}

__global__ __launch_bounds__(256) void k_pool_div(
    const float* __restrict__ gsum, const float* __restrict__ gcnt,
    float* __restrict__ emb, int gtot)
{
  int gid = blockIdx.x * blockDim.x + threadIdx.x;
  if (gid >= gtot * DD) return;
  int g = gid >> 6;
  emb[gid] = gsum[gid] / fmaxf(gcnt[g], 1.0f);
}

extern "C" void kernel_launch(void* const* d_in, const int* in_sizes, int n_in,
                              void* d_out, int out_size, void* d_ws, size_t ws_size,
                              hipStream_t stream)
{
  const float* x_in  = (const float*)d_in[0];
  const int*   ei    = (const int*)  d_in[1];
  const int*   batch = (const int*)  d_in[2];
  const float* Wq = (const float*)d_in[3];
  const float* bq = (const float*)d_in[4];
  const float* Wk = (const float*)d_in[5];
  const float* bk = (const float*)d_in[6];
  const float* Wv = (const float*)d_in[7];
  const float* bv = (const float*)d_in[8];
  const float* Ws = (const float*)d_in[9];
  const float* bs = (const float*)d_in[10];

  const int nd     = in_sizes[0];             // N*D
  const int n      = nd / DD;                 // N
  const int ecnt   = in_sizes[1] / 2;         // E
  const int layers = in_sizes[3] / (DD * DD); // L
  const int gtot   = (out_size - nd) / DD;    // G

  const int* src = ei;
  const int* dst = ei + ecnt;

  float* P0 = (float*)d_ws;
  float* P1 = P0 + (size_t)nd;
  float* Q  = P1 + (size_t)nd;
  float* K  = Q  + (size_t)nd;
  float* V  = K  + (size_t)nd;
  int* rowptr = (int*)(V + (size_t)nd);       // N+1
  int* deg    = rowptr + (size_t)(n + 1);     // N (also used as fill cursor)
  int* adj    = deg + (size_t)n;              // E
  float* gsum = (float*)(adj + (size_t)ecnt); // G*D
  float* gcnt = gsum + (size_t)gtot * DD;     // G

  float* out = (float*)d_out;

  // ---- CSR build (dst-grouped) ----
  hipMemsetAsync(deg, 0, (size_t)n * 4, stream);
  const int ebs = (ecnt + 255) / 256;
  k_hist<<<min(ebs, 2048), 256, 0, stream>>>(dst, deg, ecnt);
  k_scan<<<1, 1024, 0, stream>>>(deg, rowptr, n);
  hipMemsetAsync(deg, 0, (size_t)n * 4, stream);
  k_fill<<<min(ebs, 2048), 256, 0, stream>>>(src, dst, rowptr, deg, adj, ecnt);

  const int pb = (n * 16 + 255) / 256;
  const int nb = (n * 64 + 255) / 256;

  const float* xcur = x_in;
  for (int l = 0; l < layers; ++l) {
    float* xnext = (l == layers - 1) ? out : ((l & 1) ? P1 : P0);
    const size_t wo = (size_t)l * DD * DD;
    const size_t bo = (size_t)l * DD;
    k_proj3<<<pb, 256, 0, stream>>>(xcur, Wq + wo, bq + bo, Q,
                                    Wk + wo, bk + bo, K,
                                    Wv + wo, bv + bo, V, n);
    k_node<<<nb, 256, 0, stream>>>(Q, K, V, xcur, Ws + wo, bs + bo,
                                   rowptr, adj, xnext, n);
    xcur = xnext;
  }

  hipMemsetAsync(gsum, 0, (size_t)gtot * DD * 4, stream);
  hipMemsetAsync(gcnt, 0, (size_t)gtot * 4, stream);
  const int pbk = (n + 63) / 64;
  k_pool_sum<<<pbk, 64, 0, stream>>>(out, batch, gsum, gcnt, n);
  const int fb = (gtot * DD + 255) / 256;
  k_pool_div<<<fb, 256, 0, stream>>>(gsum, gcnt, out + (size_t)nd, gtot);
}

// Round 3
// 706.331 us; speedup vs baseline: 5.9415x; 1.8212x over previous
//
#include <hip/hip_runtime.h>
#include <math.h>

#define DD 64   // feature dim

// ---- fused projection: Q,K,V = x@W*+b*, S = x@Ws+bs (skip), W staged in LDS.
// 256 threads/WG, 64 nodes/WG: thread = (nodegroup 0..15, t 0..15),
// computes 4 nodes x 4 cols for all 4 matrices.
__global__ __launch_bounds__(256) void k_proj4(
    const float* __restrict__ x,
    const float* __restrict__ Wq, const float* __restrict__ bq, float* __restrict__ q,
    const float* __restrict__ Wk, const float* __restrict__ bk, float* __restrict__ k,
    const float* __restrict__ Wv, const float* __restrict__ bv, float* __restrict__ v,
    const float* __restrict__ Ws, const float* __restrict__ bs, float* __restrict__ s,
    int n)
{
  __shared__ float lw[4 * DD * DD];   // 64 KB: Wq | Wk | Wv | Ws
  const int tid = threadIdx.x;
  // stage 4x16KB
  #pragma unroll
  for (int r = 0; r < 4; ++r) {
    int idx = r * 256 + tid;          // float4 index within one matrix
    ((float4*)lw)[idx]          = ((const float4*)Wq)[idx];
    ((float4*)lw)[1024 + idx]   = ((const float4*)Wk)[idx];
    ((float4*)lw)[2048 + idx]   = ((const float4*)Wv)[idx];
    ((float4*)lw)[3072 + idx]   = ((const float4*)Ws)[idx];
  }
  __syncthreads();

  const int t4 = (tid & 15) << 2;
  const int nbase = blockIdx.x * 64 + (tid >> 4) * 4;
  if (nbase >= n) return;

  float4 aq[4], ak[4], av[4], as_[4];
  const float4 bq4 = *(const float4*)(bq + t4);
  const float4 bk4 = *(const float4*)(bk + t4);
  const float4 bv4 = *(const float4*)(bv + t4);
  const float4 bs4 = *(const float4*)(bs + t4);
  #pragma unroll
  for (int j = 0; j < 4; ++j) { aq[j] = bq4; ak[j] = bk4; av[j] = bv4; as_[j] = bs4; }

  int nj[4];
  #pragma unroll
  for (int j = 0; j < 4; ++j) nj[j] = min(nbase + j, n - 1);

  for (int ic = 0; ic < 16; ++ic) {
    float4 xv[4];
    #pragma unroll
    for (int j = 0; j < 4; ++j)
      xv[j] = *(const float4*)(x + (size_t)nj[j] * DD + ic * 4);
    #pragma unroll
    for (int u = 0; u < 4; ++u) {
      const float* lp = lw + (ic * 4 + u) * DD + t4;
      float4 wq = *(const float4*)(lp);
      float4 wk = *(const float4*)(lp + DD * DD);
      float4 wv = *(const float4*)(lp + 2 * DD * DD);
      float4 ws = *(const float4*)(lp + 3 * DD * DD);
      #pragma unroll
      for (int j = 0; j < 4; ++j) {
        float xi = (&xv[j].x)[u];
        aq[j].x = fmaf(xi, wq.x, aq[j].x); aq[j].y = fmaf(xi, wq.y, aq[j].y);
        aq[j].z = fmaf(xi, wq.z, aq[j].z); aq[j].w = fmaf(xi, wq.w, aq[j].w);
        ak[j].x = fmaf(xi, wk.x, ak[j].x); ak[j].y = fmaf(xi, wk.y, ak[j].y);
        ak[j].z = fmaf(xi, wk.z, ak[j].z); ak[j].w = fmaf(xi, wk.w, ak[j].w);
        av[j].x = fmaf(xi, wv.x, av[j].x); av[j].y = fmaf(xi, wv.y, av[j].y);
        av[j].z = fmaf(xi, wv.z, av[j].z); av[j].w = fmaf(xi, wv.w, av[j].w);
        as_[j].x = fmaf(xi, ws.x, as_[j].x); as_[j].y = fmaf(xi, ws.y, as_[j].y);
        as_[j].z = fmaf(xi, ws.z, as_[j].z); as_[j].w = fmaf(xi, ws.w, as_[j].w);
      }
    }
  }
  #pragma unroll
  for (int j = 0; j < 4; ++j) {
    int node = nbase + j;
    if (node < n) {
      size_t o = (size_t)node * DD + t4;
      *(float4*)(q + o) = aq[j];
      *(float4*)(k + o) = ak[j];
      *(float4*)(v + o) = av[j];
      *(float4*)(s + o) = as_[j];
    }
  }
}

// ---- CSR build (once per call) ----
__global__ __launch_bounds__(256) void k_hist(
    const int* __restrict__ dst, int* __restrict__ deg, int ecnt)
{
  for (int e = blockIdx.x * blockDim.x + threadIdx.x; e < ecnt;
       e += gridDim.x * blockDim.x)
    atomicAdd(deg + dst[e], 1);
}

__global__ __launch_bounds__(1024) void k_scan(
    const int* __restrict__ deg, int* __restrict__ rowptr, int n)
{
  __shared__ int wsum[16];
  int lane = threadIdx.x & 63;
  int wave = threadIdx.x >> 6;
  if (threadIdx.x == 0) rowptr[0] = 0;
  int carry = 0;
  for (int base = 0; base < n; base += 1024) {
    int i = base + threadIdx.x;
    int val = (i < n) ? deg[i] : 0;
    int s = val;
    #pragma unroll
    for (int off = 1; off < 64; off <<= 1) {
      int t = __shfl_up(s, off);
      if (lane >= off) s += t;
    }
    if (lane == 63) wsum[wave] = s;
    __syncthreads();
    if (wave == 0) {
      int ws = (lane < 16) ? wsum[lane] : 0;
      #pragma unroll
      for (int off = 1; off < 16; off <<= 1) {
        int t = __shfl_up(ws, off);
        if (lane >= off) ws += t;
      }
      if (lane < 16) wsum[lane] = ws;
    }
    __syncthreads();
    int woff = (wave > 0) ? wsum[wave - 1] : 0;
    if (i < n) rowptr[i + 1] = carry + woff + s;
    carry += wsum[15];
    __syncthreads();
  }
}

__global__ __launch_bounds__(256) void k_fill(
    const int* __restrict__ src, const int* __restrict__ dst,
    const int* __restrict__ rowptr, int* __restrict__ cur,
    int* __restrict__ adj, int ecnt)
{
  for (int e = blockIdx.x * blockDim.x + threadIdx.x; e < ecnt;
       e += gridDim.x * blockDim.x) {
    int d = dst[e];
    int pos = rowptr[d] + atomicAdd(cur + d, 1);
    adj[pos] = src[e];
  }
}

// ---- one wave per dst node, 4 edges per iteration.
// lane = (g 0..3, t 0..15); group g handles edge chunk_base+g with float4 rows.
// skip S precomputed by k_proj4 lives in `out`; read it, add, relu, overwrite.
__global__ __launch_bounds__(256) void k_node(
    const float* __restrict__ q, const float* __restrict__ k,
    const float* __restrict__ v,
    const int* __restrict__ rowptr, const int* __restrict__ adj,
    float* __restrict__ out, int n)
{
  int node = (blockIdx.x * blockDim.x + threadIdx.x) >> 6;
  int lane = threadIdx.x & 63;
  if (node >= n) return;
  const int g = lane >> 4;
  const int t4 = (lane & 15) << 2;

  const float4 qv = *(const float4*)(q + (size_t)node * DD + t4);
  const int e0 = rowptr[node], e1 = rowptr[node + 1];

  float m = -INFINITY, denom = 0.f;
  float4 agg = make_float4(0.f, 0.f, 0.f, 0.f);

  for (int base = e0; base < e1; base += 4) {
    int ei = base + g;
    bool valid = (ei < e1);
    int s = adj[valid ? ei : e1 - 1];
    const float4 kv = *(const float4*)(k + (size_t)s * DD + t4);
    const float4 vv = *(const float4*)(v + (size_t)s * DD + t4);
    float p = qv.x * kv.x + qv.y * kv.y + qv.z * kv.z + qv.w * kv.w;
    p += __shfl_xor(p, 1);
    p += __shfl_xor(p, 2);
    p += __shfl_xor(p, 4);
    p += __shfl_xor(p, 8);
    p *= 0.125f;                 // 1/sqrt(64)
    if (!valid) p = -INFINITY;
    float cm = fmaxf(p, __shfl_xor(p, 16));
    cm = fmaxf(cm, __shfl_xor(cm, 32));   // wave-uniform chunk max
    if (cm > m) {                          // wave-uniform branch
      float cc = __expf(m - cm);           // first chunk: exp(-inf)=0
      denom *= cc;
      agg.x *= cc; agg.y *= cc; agg.z *= cc; agg.w *= cc;
      m = cm;
    }
    float w = __expf(p - m);               // invalid: exp(-inf)=0
    denom += w;
    agg.x = fmaf(w, vv.x, agg.x); agg.y = fmaf(w, vv.y, agg.y);
    agg.z = fmaf(w, vv.z, agg.z); agg.w = fmaf(w, vv.w, agg.w);
  }

  // reduce across the 4 groups
  denom += __shfl_xor(denom, 16); denom += __shfl_xor(denom, 32);
  agg.x += __shfl_xor(agg.x, 16); agg.y += __shfl_xor(agg.y, 16);
  agg.z += __shfl_xor(agg.z, 16); agg.w += __shfl_xor(agg.w, 16);
  agg.x += __shfl_xor(agg.x, 32); agg.y += __shfl_xor(agg.y, 32);
  agg.z += __shfl_xor(agg.z, 32); agg.w += __shfl_xor(agg.w, 32);

  float4 s4 = *(const float4*)(out + (size_t)node * DD + t4);  // skip (read before write)
  float inv = (denom > 0.f) ? (1.0f / denom) : 0.f;
  if (g == 0) {
    float4 r;
    r.x = fmaxf(fmaf(agg.x, inv, s4.x), 0.f);
    r.y = fmaxf(fmaf(agg.y, inv, s4.y), 0.f);
    r.z = fmaxf(fmaf(agg.z, inv, s4.z), 0.f);
    r.w = fmaxf(fmaf(agg.w, inv, s4.w), 0.f);
    *(float4*)(out + (size_t)node * DD + t4) = r;
  }
}

// batch is sorted: run-length accumulate per wave (64 dims), flush on graph change
__global__ __launch_bounds__(64) void k_pool_sum(
    const float* __restrict__ x, const int* __restrict__ batch,
    float* __restrict__ gsum, float* __restrict__ gcnt, int n)
{
  int lane = threadIdx.x;
  int n0 = blockIdx.x * 64;
  if (n0 >= n) return;
  int n1 = min(n0 + 64, n);
  float acc = 0.f;
  int g_prev = batch[n0];
  int run = 0;
  for (int nn = n0; nn < n1; ++nn) {
    int g = batch[nn];
    if (g != g_prev) {
      atomicAdd(gsum + (size_t)g_prev * DD + lane, acc);
      if (lane == 0) atomicAdd(gcnt + g_prev, (float)run);
      acc = 0.f; run = 0; g_prev = g;
    }
    acc += x[(size_t)nn * DD + lane];
    run++;
  }
  atomicAdd(gsum + (size_t)g_prev * DD + lane, acc);
  if (lane == 0) atomicAdd(gcnt + g_prev, (float)run);
}

__global__ __launch_bounds__(256) void k_pool_div(
    const float* __restrict__ gsum, const float* __restrict__ gcnt,
    float* __restrict__ emb, int gtot)
{
  int gid = blockIdx.x * blockDim.x + threadIdx.x;
  if (gid >= gtot * DD) return;
  int g = gid >> 6;
  emb[gid] = gsum[gid] / fmaxf(gcnt[g], 1.0f);
}

extern "C" void kernel_launch(void* const* d_in, const int* in_sizes, int n_in,
                              void* d_out, int out_size, void* d_ws, size_t ws_size,
                              hipStream_t stream)
{
  const float* x_in  = (const float*)d_in[0];
  const int*   ei    = (const int*)  d_in[1];
  const int*   batch = (const int*)  d_in[2];
  const float* Wq = (const float*)d_in[3];
  const float* bq = (const float*)d_in[4];
  const float* Wk = (const float*)d_in[5];
  const float* bk = (const float*)d_in[6];
  const float* Wv = (const float*)d_in[7];
  const float* bv = (const float*)d_in[8];
  const float* Ws = (const float*)d_in[9];
  const float* bs = (const float*)d_in[10];

  const int nd     = in_sizes[0];             // N*D
  const int n      = nd / DD;                 // N
  const int ecnt   = in_sizes[1] / 2;         // E
  const int layers = in_sizes[3] / (DD * DD); // L
  const int gtot   = (out_size - nd) / DD;    // G

  const int* src = ei;
  const int* dst = ei + ecnt;

  float* P0 = (float*)d_ws;
  float* P1 = P0 + (size_t)nd;
  float* Q  = P1 + (size_t)nd;
  float* K  = Q  + (size_t)nd;
  float* V  = K  + (size_t)nd;
  int* rowptr = (int*)(V + (size_t)nd);       // N+1
  int* deg    = rowptr + (size_t)(n + 1);     // N (also fill cursor)
  int* adj    = deg + (size_t)n;              // E
  float* gsum = (float*)(adj + (size_t)ecnt); // G*D
  float* gcnt = gsum + (size_t)gtot * DD;     // G

  float* out = (float*)d_out;

  // ---- CSR build (dst-grouped) ----
  hipMemsetAsync(deg, 0, (size_t)n * 4, stream);
  const int ebs = (ecnt + 255) / 256;
  k_hist<<<min(ebs, 2048), 256, 0, stream>>>(dst, deg, ecnt);
  k_scan<<<1, 1024, 0, stream>>>(deg, rowptr, n);
  hipMemsetAsync(deg, 0, (size_t)n * 4, stream);
  k_fill<<<min(ebs, 2048), 256, 0, stream>>>(src, dst, rowptr, deg, adj, ecnt);

  const int pj = (n + 63) / 64;
  const int nb = (n * 64 + 255) / 256;

  const float* xcur = x_in;
  for (int l = 0; l < layers; ++l) {
    float* xnext = (l == layers - 1) ? out : ((l & 1) ? P1 : P0);
    const size_t wo = (size_t)l * DD * DD;
    const size_t bo = (size_t)l * DD;
    k_proj4<<<pj, 256, 0, stream>>>(xcur, Wq + wo, bq + bo, Q,
                                    Wk + wo, bk + bo, K,
                                    Wv + wo, bv + bo, V,
                                    Ws + wo, bs + bo, xnext, n);
    k_node<<<nb, 256, 0, stream>>>(Q, K, V, rowptr, adj, xnext, n);
    xcur = xnext;
  }

  hipMemsetAsync(gsum, 0, (size_t)gtot * DD * 4, stream);
  hipMemsetAsync(gcnt, 0, (size_t)gtot * 4, stream);
  const int pbk = (n + 63) / 64;
  k_pool_sum<<<pbk, 64, 0, stream>>>(out, batch, gsum, gcnt, n);
  const int fb = (gtot * DD + 255) / 256;
  k_pool_div<<<fb, 256, 0, stream>>>(gsum, gcnt, out + (size_t)nd, gtot);
}

// Round 4
// 405.342 us; speedup vs baseline: 10.3535x; 1.7426x over previous
//
#include <hip/hip_runtime.h>
#include <math.h>

#define DD 64   // feature dim

typedef _Float16 h2 __attribute__((ext_vector_type(2)));
typedef _Float16 h8 __attribute__((ext_vector_type(8)));
typedef float f32x4 __attribute__((ext_vector_type(4)));

// ---- W -> MFMA B-fragment pre-shuffle (fp16), all layers at once ----
// wf layout: [layer][colTile c:16][kstep s:2][lane:64][j:8]
// element = B[k = s*32 + (lane>>4)*8 + j][col = c*16 + (lane&15)]
// where B = [Wq | Wk | Wv | Ws] columns (256 cols)
__global__ __launch_bounds__(64) void k_wconv(
    const float* __restrict__ Wq, const float* __restrict__ Wk,
    const float* __restrict__ Wv, const float* __restrict__ Ws,
    _Float16* __restrict__ wf)
{
  int bid = blockIdx.x;          // layer*32 + c*2 + s
  int layer = bid >> 5;
  int c = (bid >> 1) & 15;
  int s = bid & 1;
  int lane = threadIdx.x;
  int col = c * 16 + (lane & 15);
  int mi = col >> 6;
  const float* W = (mi == 0 ? Wq : mi == 1 ? Wk : mi == 2 ? Wv : Ws)
                   + (size_t)layer * DD * DD;
  int colw = col & 63;
  _Float16* o = wf + ((((size_t)(layer * 16 + c)) * 2 + s) * 64 + lane) * 8;
  #pragma unroll
  for (int j = 0; j < 8; ++j) {
    int k = s * 32 + (lane >> 4) * 8 + j;
    o[j] = (_Float16)W[k * DD + colw];
  }
}

// fp32 -> fp16 convert (8 elems/thread)
__global__ __launch_bounds__(256) void k_xconv(
    const float* __restrict__ x, _Float16* __restrict__ xb, int total8)
{
  int i = blockIdx.x * 256 + threadIdx.x;
  if (i >= total8) return;
  float4 a = ((const float4*)x)[i * 2];
  float4 b = ((const float4*)x)[i * 2 + 1];
  h8 o;
  o[0] = (_Float16)a.x; o[1] = (_Float16)a.y; o[2] = (_Float16)a.z; o[3] = (_Float16)a.w;
  o[4] = (_Float16)b.x; o[5] = (_Float16)b.y; o[6] = (_Float16)b.z; o[7] = (_Float16)b.w;
  *(h8*)(xb + (size_t)i * 8) = o;
}

// ---- MFMA projection: [Q|K|V|S] = xb @ Wcat + b. One WG = 64 nodes, 4 waves.
// Outputs: qh fp16 [n][64], kvh fp16 [n][128] (K|V), sout fp32 [n][64] (skip).
__global__ __launch_bounds__(256) void k_projM(
    const _Float16* __restrict__ xb, const _Float16* __restrict__ wf,
    const float* __restrict__ bq, const float* __restrict__ bk,
    const float* __restrict__ bv, const float* __restrict__ bs,
    _Float16* __restrict__ qh, _Float16* __restrict__ kvh,
    float* __restrict__ sout, int n)
{
  int wave = threadIdx.x >> 6;
  int lane = threadIdx.x & 63;
  int nbase = blockIdx.x * 64 + wave * 16;
  if (nbase >= n) return;

  int ar = min(nbase + (lane & 15), n - 1);
  h8 a0 = *(const h8*)(xb + (size_t)ar * DD + (lane >> 4) * 8);
  h8 a1 = *(const h8*)(xb + (size_t)ar * DD + 32 + (lane >> 4) * 8);

  const int cl = lane & 15;
  const int rq = lane >> 4;
  const bool ev = (lane & 1) == 0;

  for (int c = 0; c < 16; ++c) {
    const float* bp = (c < 4) ? bq : (c < 8) ? bk : (c < 12) ? bv : bs;
    int col = c * 16 + cl;
    float bcol = bp[col & 63];
    f32x4 acc = {bcol, bcol, bcol, bcol};
    const _Float16* wp = wf + ((size_t)(c * 2) * 64 + lane) * 8;
    h8 b0 = *(const h8*)(wp);
    h8 b1 = *(const h8*)(wp + 64 * 8);
    acc = __builtin_amdgcn_mfma_f32_16x16x32_f16(a0, b0, acc, 0, 0, 0);
    acc = __builtin_amdgcn_mfma_f32_16x16x32_f16(a1, b1, acc, 0, 0, 0);

    if (c < 12) {
      // fp16 outputs: pack adjacent cols in even lanes, 4B stores
      #pragma unroll
      for (int r = 0; r < 4; ++r) {
        float other = __shfl_xor(acc[r], 1);
        int node_r = nbase + rq * 4 + r;
        if (ev && node_r < n) {
          h2 p; p.x = (_Float16)acc[r]; p.y = (_Float16)other;
          unsigned u = __builtin_bit_cast(unsigned, p);
          if (c < 4)
            *(unsigned*)(qh + (size_t)node_r * DD + col) = u;
          else
            *(unsigned*)(kvh + (size_t)node_r * 128 + (col - 64)) = u;
        }
      }
    } else {
      #pragma unroll
      for (int r = 0; r < 4; ++r) {
        int node_r = nbase + rq * 4 + r;
        if (node_r < n)
          sout[(size_t)node_r * DD + (col - 192)] = acc[r];
      }
    }
  }
}

// ---- CSR build ----
__global__ __launch_bounds__(256) void k_hist(
    const int* __restrict__ dst, int* __restrict__ deg,
    int* __restrict__ pos, int ecnt)
{
  for (int e = blockIdx.x * blockDim.x + threadIdx.x; e < ecnt;
       e += gridDim.x * blockDim.x)
    pos[e] = atomicAdd(deg + dst[e], 1);
}

// exclusive scan, 1 WG, 4 elems/thread per pass
__global__ __launch_bounds__(1024) void k_scan(
    const int* __restrict__ deg, int* __restrict__ rowptr, int n)
{
  __shared__ int wsum[16];
  int lane = threadIdx.x & 63;
  int wave = threadIdx.x >> 6;
  if (threadIdx.x == 0) rowptr[0] = 0;
  int carry = 0;
  for (int base = 0; base < n; base += 4096) {
    int i = base + threadIdx.x * 4;
    int4 d = make_int4(0, 0, 0, 0);
    if (i + 3 < n) d = *(const int4*)(deg + i);
    else {
      if (i     < n) d.x = deg[i];
      if (i + 1 < n) d.y = deg[i + 1];
      if (i + 2 < n) d.z = deg[i + 2];
    }
    int s1 = d.x, s2 = s1 + d.y, s3 = s2 + d.z, s4 = s3 + d.w;
    int s = s4;
    #pragma unroll
    for (int off = 1; off < 64; off <<= 1) {
      int t = __shfl_up(s, off);
      if (lane >= off) s += t;
    }
    if (lane == 63) wsum[wave] = s;
    __syncthreads();
    if (wave == 0) {
      int ws = (lane < 16) ? wsum[lane] : 0;
      #pragma unroll
      for (int off = 1; off < 16; off <<= 1) {
        int t = __shfl_up(ws, off);
        if (lane >= off) ws += t;
      }
      if (lane < 16) wsum[lane] = ws;
    }
    __syncthreads();
    int excl = carry + ((wave > 0) ? wsum[wave - 1] : 0) + s - s4;
    if (i     < n) rowptr[i + 1] = excl + s1;
    if (i + 1 < n) rowptr[i + 2] = excl + s2;
    if (i + 2 < n) rowptr[i + 3] = excl + s3;
    if (i + 3 < n) rowptr[i + 4] = excl + s4;
    carry += wsum[15];
    __syncthreads();
  }
}

// atomic-free fill using precomputed pos
__global__ __launch_bounds__(256) void k_fill(
    const int* __restrict__ src, const int* __restrict__ dst,
    const int* __restrict__ rowptr, const int* __restrict__ pos,
    int* __restrict__ adj, int ecnt)
{
  for (int e = blockIdx.x * blockDim.x + threadIdx.x; e < ecnt;
       e += gridDim.x * blockDim.x)
    adj[rowptr[dst[e]] + pos[e]] = src[e];
}

// ---- one wave per dst node, 8 edges/iter, 8 lanes/edge, fp16 KV gathers.
// skip S (fp32) precomputed in `out`; add, relu, overwrite; also emit fp16 x.
__global__ __launch_bounds__(256) void k_node(
    const _Float16* __restrict__ qh, const _Float16* __restrict__ kvh,
    const int* __restrict__ rowptr, const int* __restrict__ adj,
    float* __restrict__ out, _Float16* __restrict__ xbnext, int n)
{
  int node = (blockIdx.x * blockDim.x + threadIdx.x) >> 6;
  int lane = threadIdx.x & 63;
  if (node >= n) return;
  const int g = lane >> 3;   // sub-edge 0..7
  const int t = lane & 7;    // dim-chunk 0..7 (dims 8t..8t+7)

  const h2* qp = (const h2*)(qh + (size_t)node * DD + t * 8);
  h2 q0 = qp[0], q1 = qp[1], q2 = qp[2], q3 = qp[3];

  int e0 = rowptr[node], e1 = rowptr[node + 1];
  float m = -INFINITY, denom = 0.f;
  float agg[8] = {0.f, 0.f, 0.f, 0.f, 0.f, 0.f, 0.f, 0.f};

  for (int base = e0; base < e1; base += 8) {
    int ei = base + g;
    bool valid = (ei < e1);
    int s = adj[valid ? ei : e1 - 1];
    const h2* kp = (const h2*)(kvh + (size_t)s * 128 + t * 8);
    const h2* vp = kp + 32;   // +64 halves
    h2 k0 = kp[0], k1 = kp[1], k2 = kp[2], k3 = kp[3];
    h2 v0 = vp[0], v1 = vp[1], v2 = vp[2], v3 = vp[3];

    h2 ph = q0 * k0;
    ph = q1 * k1 + ph;
    ph = q2 * k2 + ph;
    ph = q3 * k3 + ph;
    float p = (float)ph.x + (float)ph.y;
    p += __shfl_xor(p, 1);
    p += __shfl_xor(p, 2);
    p += __shfl_xor(p, 4);
    p *= 0.125f;                       // 1/sqrt(64)
    if (!valid) p = -INFINITY;
    float cm = fmaxf(p, __shfl_xor(p, 8));
    cm = fmaxf(cm, __shfl_xor(cm, 16));
    cm = fmaxf(cm, __shfl_xor(cm, 32));   // wave-uniform chunk max
    if (cm > m) {
      float cc = __expf(m - cm);
      denom *= cc;
      #pragma unroll
      for (int j = 0; j < 8; ++j) agg[j] *= cc;
      m = cm;
    }
    float w = __expf(p - m);
    denom += w;
    agg[0] = fmaf(w, (float)v0.x, agg[0]); agg[1] = fmaf(w, (float)v0.y, agg[1]);
    agg[2] = fmaf(w, (float)v1.x, agg[2]); agg[3] = fmaf(w, (float)v1.y, agg[3]);
    agg[4] = fmaf(w, (float)v2.x, agg[4]); agg[5] = fmaf(w, (float)v2.y, agg[5]);
    agg[6] = fmaf(w, (float)v3.x, agg[6]); agg[7] = fmaf(w, (float)v3.y, agg[7]);
  }

  denom += __shfl_xor(denom, 8);
  denom += __shfl_xor(denom, 16);
  denom += __shfl_xor(denom, 32);
  #pragma unroll
  for (int j = 0; j < 8; ++j) {
    agg[j] += __shfl_xor(agg[j], 8);
    agg[j] += __shfl_xor(agg[j], 16);
    agg[j] += __shfl_xor(agg[j], 32);
  }

  if (g == 0) {
    float inv = (denom > 0.f) ? (1.0f / denom) : 0.f;
    float* op = out + (size_t)node * DD + t * 8;
    float4 sa = *(const float4*)(op);
    float4 sb = *(const float4*)(op + 4);
    float r[8];
    r[0] = fmaxf(fmaf(agg[0], inv, sa.x), 0.f);
    r[1] = fmaxf(fmaf(agg[1], inv, sa.y), 0.f);
    r[2] = fmaxf(fmaf(agg[2], inv, sa.z), 0.f);
    r[3] = fmaxf(fmaf(agg[3], inv, sa.w), 0.f);
    r[4] = fmaxf(fmaf(agg[4], inv, sb.x), 0.f);
    r[5] = fmaxf(fmaf(agg[5], inv, sb.y), 0.f);
    r[6] = fmaxf(fmaf(agg[6], inv, sb.z), 0.f);
    r[7] = fmaxf(fmaf(agg[7], inv, sb.w), 0.f);
    float4 oa = make_float4(r[0], r[1], r[2], r[3]);
    float4 ob = make_float4(r[4], r[5], r[6], r[7]);
    *(float4*)(op) = oa;
    *(float4*)(op + 4) = ob;
    h8 xh;
    #pragma unroll
    for (int j = 0; j < 8; ++j) xh[j] = (_Float16)r[j];
    *(h8*)(xbnext + (size_t)node * DD + t * 8) = xh;
  }
}

// batch is sorted: run-length accumulate per wave, flush on graph change
__global__ __launch_bounds__(64) void k_pool_sum(
    const float* __restrict__ x, const int* __restrict__ batch,
    float* __restrict__ gsum, float* __restrict__ gcnt, int n)
{
  int lane = threadIdx.x;
  int n0 = blockIdx.x * 64;
  if (n0 >= n) return;
  int n1 = min(n0 + 64, n);
  float acc = 0.f;
  int g_prev = batch[n0];
  int run = 0;
  for (int nn = n0; nn < n1; ++nn) {
    int g = batch[nn];
    if (g != g_prev) {
      atomicAdd(gsum + (size_t)g_prev * DD + lane, acc);
      if (lane == 0) atomicAdd(gcnt + g_prev, (float)run);
      acc = 0.f; run = 0; g_prev = g;
    }
    acc += x[(size_t)nn * DD + lane];
    run++;
  }
  atomicAdd(gsum + (size_t)g_prev * DD + lane, acc);
  if (lane == 0) atomicAdd(gcnt + g_prev, (float)run);
}

__global__ __launch_bounds__(256) void k_pool_div(
    const float* __restrict__ gsum, const float* __restrict__ gcnt,
    float* __restrict__ emb, int gtot)
{
  int gid = blockIdx.x * blockDim.x + threadIdx.x;
  if (gid >= gtot * DD) return;
  int g = gid >> 6;
  emb[gid] = gsum[gid] / fmaxf(gcnt[g], 1.0f);
}

extern "C" void kernel_launch(void* const* d_in, const int* in_sizes, int n_in,
                              void* d_out, int out_size, void* d_ws, size_t ws_size,
                              hipStream_t stream)
{
  const float* x_in  = (const float*)d_in[0];
  const int*   ei    = (const int*)  d_in[1];
  const int*   batch = (const int*)  d_in[2];
  const float* Wq = (const float*)d_in[3];
  const float* bq = (const float*)d_in[4];
  const float* Wk = (const float*)d_in[5];
  const float* bk = (const float*)d_in[6];
  const float* Wv = (const float*)d_in[7];
  const float* bv = (const float*)d_in[8];
  const float* Ws = (const float*)d_in[9];
  const float* bs = (const float*)d_in[10];

  const int nd     = in_sizes[0];             // N*D
  const int n      = nd / DD;                 // N
  const int ecnt   = in_sizes[1] / 2;         // E
  const int layers = in_sizes[3] / (DD * DD); // L
  const int gtot   = (out_size - nd) / DD;    // G

  const int* src = ei;
  const int* dst = ei + ecnt;

  // workspace layout (16B-aligned fp16/fp32 blocks first)
  char* cur = (char*)d_ws;
  float*     P0  = (float*)cur;     cur += (size_t)nd * 4;        // fp32 S/x buffer
  _Float16*  XB  = (_Float16*)cur;  cur += (size_t)nd * 2;        // fp16 x
  _Float16*  QH  = (_Float16*)cur;  cur += (size_t)nd * 2;        // fp16 Q
  _Float16*  KVH = (_Float16*)cur;  cur += (size_t)nd * 4;        // fp16 K|V
  _Float16*  WF  = (_Float16*)cur;  cur += (size_t)layers * 16384 * 2; // W frags
  int* rowptr = (int*)cur;          cur += (size_t)(n + 4) * 4;
  int* deg    = (int*)cur;          cur += (size_t)n * 4;
  int* adj    = (int*)cur;          cur += (size_t)ecnt * 4;
  int* pos    = (int*)cur;          cur += (size_t)ecnt * 4;
  float* gsum = (float*)cur;        cur += (size_t)gtot * DD * 4;
  float* gcnt = (float*)cur;

  float* out = (float*)d_out;

  // ---- one-time prep: W fragments, x fp16, CSR ----
  k_wconv<<<layers * 32, 64, 0, stream>>>(Wq, Wk, Wv, Ws, WF);
  k_xconv<<<(n * 8 + 255) / 256, 256, 0, stream>>>(x_in, XB, n * 8);
  hipMemsetAsync(deg, 0, (size_t)n * 4, stream);
  const int ebs = (ecnt + 255) / 256;
  k_hist<<<min(ebs, 2048), 256, 0, stream>>>(dst, deg, pos, ecnt);
  k_scan<<<1, 1024, 0, stream>>>(deg, rowptr, n);
  k_fill<<<min(ebs, 2048), 256, 0, stream>>>(src, dst, rowptr, pos, adj, ecnt);

  const int pj = (n + 63) / 64;
  const int nb = (n * 64 + 255) / 256;

  for (int l = 0; l < layers; ++l) {
    float* xnext = (l == layers - 1) ? out : P0;  // S goes here, k_node finalizes
    const size_t bo = (size_t)l * DD;
    k_projM<<<pj, 256, 0, stream>>>(XB, WF + (size_t)l * 16384,
                                    bq + bo, bk + bo, bv + bo, bs + bo,
                                    QH, KVH, xnext, n);
    k_node<<<nb, 256, 0, stream>>>(QH, KVH, rowptr, adj, xnext, XB, n);
  }

  hipMemsetAsync(gsum, 0, (size_t)gtot * DD * 4, stream);
  hipMemsetAsync(gcnt, 0, (size_t)gtot * 4, stream);
  const int pbk = (n + 63) / 64;
  k_pool_sum<<<pbk, 64, 0, stream>>>(out, batch, gsum, gcnt, n);
  const int fb = (gtot * DD + 255) / 256;
  k_pool_div<<<fb, 256, 0, stream>>>(gsum, gcnt, out + (size_t)nd, gtot);
}

// Round 5
// 396.653 us; speedup vs baseline: 10.5803x; 1.0219x over previous
//
#include <hip/hip_runtime.h>
#include <math.h>

#define DD 64   // feature dim

typedef _Float16 h2 __attribute__((ext_vector_type(2)));
typedef _Float16 h8 __attribute__((ext_vector_type(8)));
typedef float f32x4 __attribute__((ext_vector_type(4)));

// ---- W -> MFMA B-fragment pre-shuffle (fp16), all layers at once ----
// wf layout: [layer][colTile c:16][kstep s:2][lane:64][j:8]
// element = B[k = s*32 + (lane>>4)*8 + j][col = c*16 + (lane&15)]
// where B = [Wq | Wk | Wv | Ws] columns (256 cols)
__global__ __launch_bounds__(64) void k_wconv(
    const float* __restrict__ Wq, const float* __restrict__ Wk,
    const float* __restrict__ Wv, const float* __restrict__ Ws,
    _Float16* __restrict__ wf)
{
  int bid = blockIdx.x;          // layer*32 + c*2 + s
  int layer = bid >> 5;
  int c = (bid >> 1) & 15;
  int s = bid & 1;
  int lane = threadIdx.x;
  int col = c * 16 + (lane & 15);
  int mi = col >> 6;
  const float* W = (mi == 0 ? Wq : mi == 1 ? Wk : mi == 2 ? Wv : Ws)
                   + (size_t)layer * DD * DD;
  int colw = col & 63;
  _Float16* o = wf + ((((size_t)(layer * 16 + c)) * 2 + s) * 64 + lane) * 8;
  #pragma unroll
  for (int j = 0; j < 8; ++j) {
    int k = s * 32 + (lane >> 4) * 8 + j;
    o[j] = (_Float16)W[k * DD + colw];
  }
}

// fp32 -> fp16 convert (8 elems/thread)
__global__ __launch_bounds__(256) void k_xconv(
    const float* __restrict__ x, _Float16* __restrict__ xb, int total8)
{
  int i = blockIdx.x * 256 + threadIdx.x;
  if (i >= total8) return;
  float4 a = ((const float4*)x)[i * 2];
  float4 b = ((const float4*)x)[i * 2 + 1];
  h8 o;
  o[0] = (_Float16)a.x; o[1] = (_Float16)a.y; o[2] = (_Float16)a.z; o[3] = (_Float16)a.w;
  o[4] = (_Float16)b.x; o[5] = (_Float16)b.y; o[6] = (_Float16)b.z; o[7] = (_Float16)b.w;
  *(h8*)(xb + (size_t)i * 8) = o;
}

// ---- MFMA projection: [Q|K|V|S] = xb @ Wcat + b. One WG = 64 nodes, 4 waves.
// Outputs: qh fp16 [n][64], kvh fp16 [n][128] (K|V), sout fp32 [n][64] (skip).
__global__ __launch_bounds__(256) void k_projM(
    const _Float16* __restrict__ xb, const _Float16* __restrict__ wf,
    const float* __restrict__ bq, const float* __restrict__ bk,
    const float* __restrict__ bv, const float* __restrict__ bs,
    _Float16* __restrict__ qh, _Float16* __restrict__ kvh,
    float* __restrict__ sout, int n)
{
  int wave = threadIdx.x >> 6;
  int lane = threadIdx.x & 63;
  int nbase = blockIdx.x * 64 + wave * 16;
  if (nbase >= n) return;

  int ar = min(nbase + (lane & 15), n - 1);
  h8 a0 = *(const h8*)(xb + (size_t)ar * DD + (lane >> 4) * 8);
  h8 a1 = *(const h8*)(xb + (size_t)ar * DD + 32 + (lane >> 4) * 8);

  const int cl = lane & 15;
  const int rq = lane >> 4;
  const bool ev = (lane & 1) == 0;

  for (int c = 0; c < 16; ++c) {
    const float* bp = (c < 4) ? bq : (c < 8) ? bk : (c < 12) ? bv : bs;
    int col = c * 16 + cl;
    float bcol = bp[col & 63];
    f32x4 acc = {bcol, bcol, bcol, bcol};
    const _Float16* wp = wf + ((size_t)(c * 2) * 64 + lane) * 8;
    h8 b0 = *(const h8*)(wp);
    h8 b1 = *(const h8*)(wp + 64 * 8);
    acc = __builtin_amdgcn_mfma_f32_16x16x32_f16(a0, b0, acc, 0, 0, 0);
    acc = __builtin_amdgcn_mfma_f32_16x16x32_f16(a1, b1, acc, 0, 0, 0);

    if (c < 12) {
      // fp16 outputs: pack adjacent cols in even lanes, 4B stores
      #pragma unroll
      for (int r = 0; r < 4; ++r) {
        float other = __shfl_xor(acc[r], 1);
        int node_r = nbase + rq * 4 + r;
        if (ev && node_r < n) {
          h2 p; p.x = (_Float16)acc[r]; p.y = (_Float16)other;
          unsigned u = __builtin_bit_cast(unsigned, p);
          if (c < 4)
            *(unsigned*)(qh + (size_t)node_r * DD + col) = u;
          else
            *(unsigned*)(kvh + (size_t)node_r * 128 + (col - 64)) = u;
        }
      }
    } else {
      #pragma unroll
      for (int r = 0; r < 4; ++r) {
        int node_r = nbase + rq * 4 + r;
        if (node_r < n)
          sout[(size_t)node_r * DD + (col - 192)] = acc[r];
      }
    }
  }
}

// ---- CSR build ----
// 4 edges/thread, int4 loads; pos as ushort (max deg << 65536)
__global__ __launch_bounds__(256) void k_hist(
    const int* __restrict__ dst, int* __restrict__ deg,
    unsigned short* __restrict__ pos, int ecnt)
{
  int e = (blockIdx.x * 256 + threadIdx.x) * 4;
  if (e + 3 < ecnt) {
    int4 d = *(const int4*)(dst + e);
    pos[e]     = (unsigned short)atomicAdd(deg + d.x, 1);
    pos[e + 1] = (unsigned short)atomicAdd(deg + d.y, 1);
    pos[e + 2] = (unsigned short)atomicAdd(deg + d.z, 1);
    pos[e + 3] = (unsigned short)atomicAdd(deg + d.w, 1);
  } else {
    for (; e < ecnt; ++e)
      pos[e] = (unsigned short)atomicAdd(deg + dst[e], 1);
  }
}

// exclusive scan, 1 WG, 4 elems/thread per pass
__global__ __launch_bounds__(1024) void k_scan(
    const int* __restrict__ deg, int* __restrict__ rowptr, int n)
{
  __shared__ int wsum[16];
  int lane = threadIdx.x & 63;
  int wave = threadIdx.x >> 6;
  if (threadIdx.x == 0) rowptr[0] = 0;
  int carry = 0;
  for (int base = 0; base < n; base += 4096) {
    int i = base + threadIdx.x * 4;
    int4 d = make_int4(0, 0, 0, 0);
    if (i + 3 < n) d = *(const int4*)(deg + i);
    else {
      if (i     < n) d.x = deg[i];
      if (i + 1 < n) d.y = deg[i + 1];
      if (i + 2 < n) d.z = deg[i + 2];
    }
    int s1 = d.x, s2 = s1 + d.y, s3 = s2 + d.z, s4 = s3 + d.w;
    int s = s4;
    #pragma unroll
    for (int off = 1; off < 64; off <<= 1) {
      int t = __shfl_up(s, off);
      if (lane >= off) s += t;
    }
    if (lane == 63) wsum[wave] = s;
    __syncthreads();
    if (wave == 0) {
      int ws = (lane < 16) ? wsum[lane] : 0;
      #pragma unroll
      for (int off = 1; off < 16; off <<= 1) {
        int t = __shfl_up(ws, off);
        if (lane >= off) ws += t;
      }
      if (lane < 16) wsum[lane] = ws;
    }
    __syncthreads();
    int excl = carry + ((wave > 0) ? wsum[wave - 1] : 0) + s - s4;
    if (i     < n) rowptr[i + 1] = excl + s1;
    if (i + 1 < n) rowptr[i + 2] = excl + s2;
    if (i + 2 < n) rowptr[i + 3] = excl + s3;
    if (i + 3 < n) rowptr[i + 4] = excl + s4;
    carry += wsum[15];
    __syncthreads();
  }
}

// atomic-free fill using precomputed pos
__global__ __launch_bounds__(256) void k_fill(
    const int* __restrict__ src, const int* __restrict__ dst,
    const int* __restrict__ rowptr, const unsigned short* __restrict__ pos,
    int* __restrict__ adj, int ecnt)
{
  int e = (blockIdx.x * 256 + threadIdx.x) * 4;
  if (e + 3 < ecnt) {
    int4 d = *(const int4*)(dst + e);
    int4 s = *(const int4*)(src + e);
    ushort4 p = *(const ushort4*)(pos + e);
    adj[rowptr[d.x] + p.x] = s.x;
    adj[rowptr[d.y] + p.y] = s.y;
    adj[rowptr[d.z] + p.z] = s.z;
    adj[rowptr[d.w] + p.w] = s.w;
  } else {
    for (; e < ecnt; ++e)
      adj[rowptr[dst[e]] + pos[e]] = src[e];
  }
}

__device__ __forceinline__ h2 h2of(h8 v, int a, int b) {
  return __builtin_shufflevector(v, v, 0, 1);  // overwritten below via macro
}
#define H2OF(v, i) __builtin_shufflevector((v), (v), 2*(i), 2*(i)+1)

// ---- one wave per dst node, 8 edges/iter, 8 lanes/edge, fp16 KV gathers.
// Next chunk's adj + K/V prefetched into registers to hide gather latency.
// skip S (fp32) read from sskip; MID layers write only fp16 xbnext,
// LAST layer writes only fp32 outp.
template<bool LAST>
__global__ __launch_bounds__(256) void k_node(
    const _Float16* __restrict__ qh, const _Float16* __restrict__ kvh,
    const int* __restrict__ rowptr, const int* __restrict__ adj,
    const float* __restrict__ sskip, float* __restrict__ outp,
    _Float16* __restrict__ xbnext, int n)
{
  int node = (blockIdx.x * blockDim.x + threadIdx.x) >> 6;
  int lane = threadIdx.x & 63;
  if (node >= n) return;
  const int g = lane >> 3;   // sub-edge 0..7
  const int t = lane & 7;    // dim-chunk 0..7 (dims 8t..8t+7)

  const h8 q8 = *(const h8*)(qh + (size_t)node * DD + t * 8);
  const h2 qp0 = H2OF(q8, 0), qp1 = H2OF(q8, 1), qp2 = H2OF(q8, 2), qp3 = H2OF(q8, 3);

  const int e0 = rowptr[node], e1 = rowptr[node + 1];
  float m = -INFINITY, denom = 0.f;
  float agg[8] = {0.f, 0.f, 0.f, 0.f, 0.f, 0.f, 0.f, 0.f};

  const char* kvb = (const char*)kvh;
  h8 kP, vP;
  if (e0 < e1) {
    int ei0 = e0 + g;
    int sP = adj[ei0 < e1 ? ei0 : e1 - 1];
    kP = *(const h8*)(kvb + ((size_t)sP * 256 + t * 16));
    vP = *(const h8*)(kvb + ((size_t)sP * 256 + 128 + t * 16));
  }

  for (int base = e0; base < e1; base += 8) {
    const h8 kc = kP, vc = vP;
    const bool valid = (base + g < e1);
    const int nb2 = base + 8;
    if (nb2 < e1) {                       // prefetch next chunk
      int ei2 = nb2 + g;
      int s2 = adj[ei2 < e1 ? ei2 : e1 - 1];
      kP = *(const h8*)(kvb + ((size_t)s2 * 256 + t * 16));
      vP = *(const h8*)(kvb + ((size_t)s2 * 256 + 128 + t * 16));
    }

#if __has_builtin(__builtin_amdgcn_fdot2)
    float p = __builtin_amdgcn_fdot2(qp0, H2OF(kc, 0), 0.f, false);
    p = __builtin_amdgcn_fdot2(qp1, H2OF(kc, 1), p, false);
    p = __builtin_amdgcn_fdot2(qp2, H2OF(kc, 2), p, false);
    p = __builtin_amdgcn_fdot2(qp3, H2OF(kc, 3), p, false);
#else
    h2 ph = qp0 * H2OF(kc, 0);
    ph = qp1 * H2OF(kc, 1) + ph;
    ph = qp2 * H2OF(kc, 2) + ph;
    ph = qp3 * H2OF(kc, 3) + ph;
    float p = (float)ph.x + (float)ph.y;
#endif
    p += __shfl_xor(p, 1);
    p += __shfl_xor(p, 2);
    p += __shfl_xor(p, 4);
    p *= 0.125f;                       // 1/sqrt(64)
    if (!valid) p = -INFINITY;
    float cm = fmaxf(p, __shfl_xor(p, 8));
    cm = fmaxf(cm, __shfl_xor(cm, 16));
    cm = fmaxf(cm, __shfl_xor(cm, 32));   // wave-uniform chunk max
    if (cm > m) {
      float cc = __expf(m - cm);
      denom *= cc;
      #pragma unroll
      for (int j = 0; j < 8; ++j) agg[j] *= cc;
      m = cm;
    }
    float w = __expf(p - m);
    denom += w;
    #pragma unroll
    for (int j = 0; j < 8; ++j)
      agg[j] = fmaf(w, (float)vc[j], agg[j]);   // v_fma_mix candidates
  }

  denom += __shfl_xor(denom, 8);
  denom += __shfl_xor(denom, 16);
  denom += __shfl_xor(denom, 32);
  #pragma unroll
  for (int j = 0; j < 8; ++j) {
    agg[j] += __shfl_xor(agg[j], 8);
    agg[j] += __shfl_xor(agg[j], 16);
    agg[j] += __shfl_xor(agg[j], 32);
  }

  if (g == 0) {
    float inv = (denom > 0.f) ? (1.0f / denom) : 0.f;
    const float* sp = sskip + (size_t)node * DD + t * 8;
    float4 sa = *(const float4*)(sp);
    float4 sb = *(const float4*)(sp + 4);
    float r[8];
    r[0] = fmaxf(fmaf(agg[0], inv, sa.x), 0.f);
    r[1] = fmaxf(fmaf(agg[1], inv, sa.y), 0.f);
    r[2] = fmaxf(fmaf(agg[2], inv, sa.z), 0.f);
    r[3] = fmaxf(fmaf(agg[3], inv, sa.w), 0.f);
    r[4] = fmaxf(fmaf(agg[4], inv, sb.x), 0.f);
    r[5] = fmaxf(fmaf(agg[5], inv, sb.y), 0.f);
    r[6] = fmaxf(fmaf(agg[6], inv, sb.z), 0.f);
    r[7] = fmaxf(fmaf(agg[7], inv, sb.w), 0.f);
    if (LAST) {
      float* op = outp + (size_t)node * DD + t * 8;
      *(float4*)(op)     = make_float4(r[0], r[1], r[2], r[3]);
      *(float4*)(op + 4) = make_float4(r[4], r[5], r[6], r[7]);
    } else {
      h8 xh;
      #pragma unroll
      for (int j = 0; j < 8; ++j) xh[j] = (_Float16)r[j];
      *(h8*)(xbnext + (size_t)node * DD + t * 8) = xh;
    }
  }
}

// batch is sorted: run-length accumulate per wave, flush on graph change
__global__ __launch_bounds__(64) void k_pool_sum(
    const float* __restrict__ x, const int* __restrict__ batch,
    float* __restrict__ gsum, float* __restrict__ gcnt, int n)
{
  int lane = threadIdx.x;
  int n0 = blockIdx.x * 64;
  if (n0 >= n) return;
  int n1 = min(n0 + 64, n);
  float acc = 0.f;
  int g_prev = batch[n0];
  int run = 0;
  for (int nn = n0; nn < n1; ++nn) {
    int g = batch[nn];
    if (g != g_prev) {
      atomicAdd(gsum + (size_t)g_prev * DD + lane, acc);
      if (lane == 0) atomicAdd(gcnt + g_prev, (float)run);
      acc = 0.f; run = 0; g_prev = g;
    }
    acc += x[(size_t)nn * DD + lane];
    run++;
  }
  atomicAdd(gsum + (size_t)g_prev * DD + lane, acc);
  if (lane == 0) atomicAdd(gcnt + g_prev, (float)run);
}

__global__ __launch_bounds__(256) void k_pool_div(
    const float* __restrict__ gsum, const float* __restrict__ gcnt,
    float* __restrict__ emb, int gtot)
{
  int gid = blockIdx.x * blockDim.x + threadIdx.x;
  if (gid >= gtot * DD) return;
  int g = gid >> 6;
  emb[gid] = gsum[gid] / fmaxf(gcnt[g], 1.0f);
}

extern "C" void kernel_launch(void* const* d_in, const int* in_sizes, int n_in,
                              void* d_out, int out_size, void* d_ws, size_t ws_size,
                              hipStream_t stream)
{
  const float* x_in  = (const float*)d_in[0];
  const int*   ei    = (const int*)  d_in[1];
  const int*   batch = (const int*)  d_in[2];
  const float* Wq = (const float*)d_in[3];
  const float* bq = (const float*)d_in[4];
  const float* Wk = (const float*)d_in[5];
  const float* bk = (const float*)d_in[6];
  const float* Wv = (const float*)d_in[7];
  const float* bv = (const float*)d_in[8];
  const float* Ws = (const float*)d_in[9];
  const float* bs = (const float*)d_in[10];

  const int nd     = in_sizes[0];             // N*D
  const int n      = nd / DD;                 // N
  const int ecnt   = in_sizes[1] / 2;         // E
  const int layers = in_sizes[3] / (DD * DD); // L
  const int gtot   = (out_size - nd) / DD;    // G

  const int* src = ei;
  const int* dst = ei + ecnt;

  // workspace layout (16B-aligned blocks first)
  char* cur = (char*)d_ws;
  float*     P0  = (float*)cur;     cur += (size_t)nd * 4;        // fp32 skip S
  _Float16*  XB  = (_Float16*)cur;  cur += (size_t)nd * 2;        // fp16 x
  _Float16*  QH  = (_Float16*)cur;  cur += (size_t)nd * 2;        // fp16 Q
  _Float16*  KVH = (_Float16*)cur;  cur += (size_t)nd * 4;        // fp16 K|V
  _Float16*  WF  = (_Float16*)cur;  cur += (size_t)layers * 16384 * 2; // W frags
  int* rowptr = (int*)cur;          cur += (size_t)(n + 4) * 4;
  int* deg    = (int*)cur;          cur += (size_t)n * 4;
  int* adj    = (int*)cur;          cur += (size_t)ecnt * 4;
  unsigned short* pos = (unsigned short*)cur; cur += (size_t)ecnt * 2;
  float* gsum = (float*)cur;        cur += (size_t)gtot * DD * 4;
  float* gcnt = (float*)cur;

  float* out = (float*)d_out;

  // ---- one-time prep: W fragments, x fp16, CSR ----
  k_wconv<<<layers * 32, 64, 0, stream>>>(Wq, Wk, Wv, Ws, WF);
  k_xconv<<<(n * 8 + 255) / 256, 256, 0, stream>>>(x_in, XB, n * 8);
  hipMemsetAsync(deg, 0, (size_t)n * 4, stream);
  const int eb4 = (ecnt + 1023) / 1024;
  k_hist<<<eb4, 256, 0, stream>>>(dst, deg, pos, ecnt);
  k_scan<<<1, 1024, 0, stream>>>(deg, rowptr, n);
  k_fill<<<eb4, 256, 0, stream>>>(src, dst, rowptr, pos, adj, ecnt);

  const int pj = (n + 63) / 64;
  const int nb = (n * 64 + 255) / 256;

  for (int l = 0; l < layers; ++l) {
    const size_t bo = (size_t)l * DD;
    k_projM<<<pj, 256, 0, stream>>>(XB, WF + (size_t)l * 16384,
                                    bq + bo, bk + bo, bv + bo, bs + bo,
                                    QH, KVH, P0, n);
    if (l == layers - 1)
      k_node<true><<<nb, 256, 0, stream>>>(QH, KVH, rowptr, adj, P0, out, XB, n);
    else
      k_node<false><<<nb, 256, 0, stream>>>(QH, KVH, rowptr, adj, P0, out, XB, n);
  }

  hipMemsetAsync(gsum, 0, (size_t)gtot * DD * 4, stream);
  hipMemsetAsync(gcnt, 0, (size_t)gtot * 4, stream);
  const int pbk = (n + 63) / 64;
  k_pool_sum<<<pbk, 64, 0, stream>>>(out, batch, gsum, gcnt, n);
  const int fb = (gtot * DD + 255) / 256;
  k_pool_div<<<fb, 256, 0, stream>>>(gsum, gcnt, out + (size_t)nd, gtot);
}